// Round 1
// baseline (266.132 us; speedup 1.0000x reference)
//
#include <hip/hip_runtime.h>
#include <math.h>

#define BB 32
#define TS 8192
#define DSEG 32
#define SS 256
#define DM 256
#define NBITS 8
#define W 512

// ---------------------------------------------------------------------------
// Kernel 1: per-batch Haar coefficients.
// Layout per b (64 floats): [0]=a13, [1]=d12, [2..3]=d11, [4..7]=d10,
// [8..15]=d9, [16..31]=d8, [32..63]=d7   (offset for level with len L is L/2)
// ---------------------------------------------------------------------------
__global__ __launch_bounds__(64) void haar_kernel(const float* __restrict__ x,
                                                  float* __restrict__ hout) {
    const int b = blockIdx.x;
    const int lane = threadIdx.x;  // 0..63, single wave
    const float* xb = x + (size_t)b * TS + (size_t)lane * 128;

    float a[128];
#pragma unroll
    for (int i = 0; i < 32; ++i) {
        float4 u = *(const float4*)(xb + 4 * i);
        a[4 * i + 0] = u.x; a[4 * i + 1] = u.y;
        a[4 * i + 2] = u.z; a[4 * i + 3] = u.w;
    }
    const float is2 = 0.70710678118654752440f;  // 1/sqrt(2)
    // 7 in-register pairwise averaging levels (matches reference tree order)
#pragma unroll
    for (int len = 128; len > 1; len >>= 1) {
#pragma unroll
        for (int j = 0; j < (len >> 1); ++j)
            a[j] = (a[2 * j] + a[2 * j + 1]) * is2;
    }
    // cross-lane levels 7..13; write detail coefficients
    float val = a[0];  // a7[lane]
    float* ob = hout + b * 64;
#pragma unroll
    for (int len = 64; len > 1; len >>= 1) {
        float e = __shfl(val, 2 * lane);
        float o = __shfl(val, 2 * lane + 1);
        int half = len >> 1;
        if (lane < half) {
            ob[half + lane] = (e - o) * is2;  // detail at this level
            val = (e + o) * is2;              // approximation continues
        }
    }
    if (lane == 0) ob[0] = val;  // a13
}

// ---------------------------------------------------------------------------
// Kernel 2: one block per (b,s). 256 threads.
// ---------------------------------------------------------------------------
__global__ __launch_bounds__(256) void main_kernel(
    const float* __restrict__ x,
    const float* __restrict__ vocab,   // [256][512][32]
    const float* __restrict__ wemb,    // [131072][256]
    const float* __restrict__ hemb,    // [7][256]
    const float* __restrict__ hcoef,   // [32][64] from kernel 1
    float* __restrict__ out)           // [32][256][256] then mask [32][256]
{
    const int bs = blockIdx.x;
    const int b = bs >> 8;
    const int s = bs & 255;
    const int t = threadIdx.x;
    const int lane = t & 63;
    const int wid = t >> 6;

    __shared__ float seg[DSEG];
    __shared__ float segn[DSEG];
    __shared__ int sh_bucket;
    __shared__ unsigned long long wmin[4];
    __shared__ float rA[4], rB[4];

    const float* xs = x + (size_t)b * TS + (size_t)s * DSEG;
    if (t < DSEG) seg[t] = xs[t];
    __syncthreads();

    // --- bucket computation (wave 0) ---
    if (wid == 0) {
        float v = seg[lane & 31];
        float mn = v, mx = v, sm = v;
#pragma unroll
        for (int m = 1; m <= 16; m <<= 1) {
            mn = fminf(mn, __shfl_xor(mn, m));
            mx = fmaxf(mx, __shfl_xor(mx, m));
            sm += __shfl_xor(sm, m);
        }
        float mean = sm * (1.0f / 32.0f);
        float cm = 0.0f;
        if (lane < 8) {
            cm = ((seg[4 * lane] + seg[4 * lane + 1]) + seg[4 * lane + 2]) +
                 seg[4 * lane + 3];
            cm *= 0.25f;
        }
        unsigned long long bal = __ballot(lane < 8 && cm > mean);
        if (lane == 0) sh_bucket = (int)(bal & 0xFFull);
        if (lane < 32) segn[lane] = (v - mn) / (mx - mn + 1e-8f);
    }
    __syncthreads();
    const int bucket = sh_bucket;

    // --- L1 distance over 512 candidates: each thread handles w=t, t+256 ---
    const float* vb = vocab + (size_t)bucket * W * DSEG;
    unsigned long long best = ~0ULL;
#pragma unroll
    for (int c = 0; c < 2; ++c) {
        const int w = t + c * 256;
        const float4* cr = (const float4*)(vb + (size_t)w * DSEG);
        float dist = 0.0f;
#pragma unroll
        for (int q = 0; q < 8; ++q) {
            float4 u = cr[q];
            // sequential accumulation order d=0..31
            dist += fabsf(u.x - segn[4 * q + 0]);
            dist += fabsf(u.y - segn[4 * q + 1]);
            dist += fabsf(u.z - segn[4 * q + 2]);
            dist += fabsf(u.w - segn[4 * q + 3]);
        }
        unsigned long long key =
            ((unsigned long long)__float_as_uint(dist) << 32) | (unsigned)w;
        if (key < best) best = key;
    }
#pragma unroll
    for (int m = 1; m < 64; m <<= 1) {
        unsigned long long o = __shfl_xor(best, m);
        if (o < best) best = o;
    }
    if (lane == 0) wmin[wid] = best;
    __syncthreads();
    unsigned long long bb = wmin[0];
#pragma unroll
    for (int i = 1; i < 4; ++i)
        if (wmin[i] < bb) bb = wmin[i];
    const int bestw = (int)(bb & 0xFFFFFFFFull);

    // --- haar coefficients for this (b,s): 7 scalars ---
    const float* hb = hcoef + b * 64;
    float hk[7];
    hk[0] = hb[0];
#pragma unroll
    for (int k = 1; k <= 6; ++k)
        hk[k] = hb[(1 << (k - 1)) + (s >> (8 - (k - 1)))];

    // --- per-dim compute (d = t) ---
    float h = 0.0f;
#pragma unroll
    for (int k = 0; k < 7; ++k) h += hk[k] * hemb[k * DM + t];

    // LayerNorm(haar_embed)
    float sm = h, sq = h * h;
#pragma unroll
    for (int m = 1; m < 64; m <<= 1) {
        sm += __shfl_xor(sm, m);
        sq += __shfl_xor(sq, m);
    }
    if (lane == 0) { rA[wid] = sm; rB[wid] = sq; }
    __syncthreads();
    sm = ((rA[0] + rA[1]) + rA[2]) + rA[3];
    sq = ((rB[0] + rB[1]) + rB[2]) + rB[3];
    float mh = sm * (1.0f / 256.0f);
    float vh = fmaxf(sq * (1.0f / 256.0f) - mh * mh, 0.0f);
    float hn = (h - mh) / sqrtf(vh + 1e-5f);

    // word embedding gather
    const size_t row = (size_t)bucket * W + (size_t)bestw;
    float wv = wemb[row * DM + t];

    // positional embedding on the fly
    const float cexp = -9.210340371976184f / 256.0f;  // -ln(10000)/256
    float dv = expf((float)(t & ~1) * cexp);
    float ang = (float)s * dv;
    float pe = (t & 1) ? cosf(ang) : sinf(ang);

    float o = wv + hn + pe;

    // final LayerNorm
    __syncthreads();  // protect rA/rB reuse
    float sm2 = o, sq2 = o * o;
#pragma unroll
    for (int m = 1; m < 64; m <<= 1) {
        sm2 += __shfl_xor(sm2, m);
        sq2 += __shfl_xor(sq2, m);
    }
    if (lane == 0) { rA[wid] = sm2; rB[wid] = sq2; }
    __syncthreads();
    sm2 = ((rA[0] + rA[1]) + rA[2]) + rA[3];
    sq2 = ((rB[0] + rB[1]) + rB[2]) + rB[3];
    float mo = sm2 * (1.0f / 256.0f);
    float vo = fmaxf(sq2 * (1.0f / 256.0f) - mo * mo, 0.0f);
    float on = (o - mo) / sqrtf(vo + 1e-5f);

    out[(size_t)bs * DM + t] = on;
    if (t == 0) out[(size_t)BB * SS * DM + bs] = 1.0f;  // att_mask
}

extern "C" void kernel_launch(void* const* d_in, const int* in_sizes, int n_in,
                              void* d_out, int out_size, void* d_ws, size_t ws_size,
                              hipStream_t stream) {
    const float* x     = (const float*)d_in[0];
    const float* vocab = (const float*)d_in[1];
    const float* wemb  = (const float*)d_in[2];
    const float* hemb  = (const float*)d_in[3];
    float* out = (float*)d_out;
    float* hco = (float*)d_ws;  // 32*64 floats = 8 KB

    haar_kernel<<<BB, 64, 0, stream>>>(x, hco);
    main_kernel<<<BB * SS, 256, 0, stream>>>(x, vocab, wemb, hemb, hco, out);
}

// Round 2
// 222.615 us; speedup vs baseline: 1.1955x; 1.1955x over previous
//
#include <hip/hip_runtime.h>
#include <math.h>

#define BB 32
#define TS 8192
#define DSEG 32
#define SS 256
#define DM 256
#define W 512
#define CAP 1024

// ---------------------------------------------------------------------------
// Kernel 0: per-batch Haar coefficients (unchanged from R0).
// Layout per b (64 floats): [0]=a13, [1]=d13, [2..3]=d12, [4..7]=d11,
// [8..15]=d10, [16..31]=d9, [32..63]=d8
// ---------------------------------------------------------------------------
__global__ __launch_bounds__(64) void haar_kernel(const float* __restrict__ x,
                                                  float* __restrict__ hout) {
    const int b = blockIdx.x;
    const int lane = threadIdx.x;  // 0..63, single wave
    const float* xb = x + (size_t)b * TS + (size_t)lane * 128;

    float a[128];
#pragma unroll
    for (int i = 0; i < 32; ++i) {
        float4 u = *(const float4*)(xb + 4 * i);
        a[4 * i + 0] = u.x; a[4 * i + 1] = u.y;
        a[4 * i + 2] = u.z; a[4 * i + 3] = u.w;
    }
    const float is2 = 0.70710678118654752440f;
#pragma unroll
    for (int len = 128; len > 1; len >>= 1) {
#pragma unroll
        for (int j = 0; j < (len >> 1); ++j)
            a[j] = (a[2 * j] + a[2 * j + 1]) * is2;
    }
    float val = a[0];
    float* ob = hout + b * 64;
#pragma unroll
    for (int len = 64; len > 1; len >>= 1) {
        float e = __shfl(val, 2 * lane);
        float o = __shfl(val, 2 * lane + 1);
        int half = len >> 1;
        if (lane < half) {
            ob[half + lane] = (e - o) * is2;
            val = (e + o) * is2;
        }
    }
    if (lane == 0) ob[0] = val;
}

// ---------------------------------------------------------------------------
// Kernel 1: per-segment bucket + normalized segment. 8 segs/block, 256 thr.
// Arithmetic bit-identical to the R0 passing kernel.
// ---------------------------------------------------------------------------
__global__ __launch_bounds__(256) void prep_kernel(
    const float* __restrict__ x,
    float* __restrict__ segn_g,                 // [8192][32]
    unsigned char* __restrict__ bucketc,        // [8192]
    unsigned long long* __restrict__ bestkey)   // [8192]
{
    const int t = threadIdx.x;
    const int segBase = blockIdx.x * 8;
    __shared__ float sseg[8][32];
    sseg[t >> 5][t & 31] = x[(size_t)segBase * 32 + t];
    __syncthreads();

    const int hw = t >> 5;        // segment slot 0..7
    const int h = hw & 1;         // half within this wave
    const int l = t & 31;
    const int seg = segBase + hw;

    float v = sseg[hw][l];
    float mn = v, mx = v, sm = v;
#pragma unroll
    for (int m = 1; m <= 16; m <<= 1) {
        mn = fminf(mn, __shfl_xor(mn, m));
        mx = fmaxf(mx, __shfl_xor(mx, m));
        sm += __shfl_xor(sm, m);
    }
    float mean = sm * (1.0f / 32.0f);
    float cm = 0.0f;
    if (l < 8) {
        cm = ((sseg[hw][4 * l] + sseg[hw][4 * l + 1]) + sseg[hw][4 * l + 2]) +
             sseg[hw][4 * l + 3];
        cm *= 0.25f;
    }
    unsigned long long bal = __ballot(l < 8 && cm > mean);
    segn_g[(size_t)seg * 32 + l] = (v - mn) / (mx - mn + 1e-8f);
    if (l == 0) bucketc[seg] = (unsigned char)((bal >> (h * 32)) & 0xFF);
    if (l == 1) bestkey[seg] = ~0ULL;
}

// ---------------------------------------------------------------------------
// Kernel 2: VQ search, bucket-grouped. Block = (bucket, half). 512 threads.
// Candidate slice staged once in LDS (XOR-swizzled vs 128B-stride conflicts).
// ---------------------------------------------------------------------------
__global__ __launch_bounds__(512) void search_kernel(
    const float* __restrict__ vocab,            // [256][512][32]
    const float* __restrict__ segn_g,
    const unsigned char* __restrict__ bucketc,
    unsigned long long* __restrict__ bestkey)
{
    const int bucket = blockIdx.x >> 1;
    const int half = blockIdx.x & 1;
    const int t = threadIdx.x;
    const int lane = t & 63;
    const int wid = t >> 6;

    __shared__ float vsh[256 * 32];   // 32 KB, swizzled
    __shared__ int list[CAP];
    __shared__ int cnt;
    if (t == 0) cnt = 0;
    __syncthreads();

    // scan for members of this bucket
    for (int i = t; i < BB * SS; i += 512) {
        if (bucketc[i] == (unsigned char)bucket) {
            int p = atomicAdd(&cnt, 1);
            if (p < CAP) list[p] = i;
        }
    }

    // stage candidate half-slice: 256 rows x 32 floats
    const float* vb = vocab + ((size_t)bucket * W + (size_t)half * 256) * DSEG;
#pragma unroll 2
    for (int f = t; f < 2048; f += 512) {     // float4 index
        int r = f >> 3, q = f & 7;
        float4 u = ((const float4*)vb)[f];
        int sq = q ^ (r & 7);
        *(float4*)&vsh[r * 32 + sq * 4] = u;
    }
    __syncthreads();

    int n = cnt; if (n > CAP) n = CAP;
    for (int i = wid; i < n; i += 8) {
        const int seg = list[i];
        const float* sp = segn_g + (size_t)seg * 32;
        float sv[32];
#pragma unroll
        for (int d = 0; d < 32; ++d) sv[d] = sp[d];

        unsigned long long best = ~0ULL;
#pragma unroll
        for (int c = 0; c < 4; ++c) {
            const int r = c * 64 + lane;
            float dist = 0.0f;
#pragma unroll
            for (int q = 0; q < 8; ++q) {
                float4 u = *(const float4*)&vsh[r * 32 + ((q ^ (r & 7)) * 4)];
                // sequential accumulation order d=0..31 (matches R0 exactly)
                dist += fabsf(u.x - sv[4 * q + 0]);
                dist += fabsf(u.y - sv[4 * q + 1]);
                dist += fabsf(u.z - sv[4 * q + 2]);
                dist += fabsf(u.w - sv[4 * q + 3]);
            }
            unsigned w = (unsigned)(half * 256 + r);
            unsigned long long key =
                ((unsigned long long)__float_as_uint(dist) << 32) | w;
            if (key < best) best = key;
        }
#pragma unroll
        for (int m = 1; m < 64; m <<= 1) {
            unsigned long long o = __shfl_xor(best, m);
            if (o < best) best = o;
        }
        if (lane == 0) atomicMin(bestkey + seg, best);
    }
}

// ---------------------------------------------------------------------------
// Kernel 3: gather + haar matvec + pos emb + 2x LayerNorm. One block/(b,s).
// ---------------------------------------------------------------------------
__global__ __launch_bounds__(256) void out_kernel(
    const float* __restrict__ wemb,     // [131072][256]
    const float* __restrict__ hemb,     // [7][256]
    const float* __restrict__ hcoef,    // [32][64]
    const unsigned char* __restrict__ bucketc,
    const unsigned long long* __restrict__ bestkey,
    float* __restrict__ out)
{
    const int bs = blockIdx.x;
    const int b = bs >> 8;
    const int s = bs & 255;
    const int t = threadIdx.x;
    const int lane = t & 63;
    const int wid = t >> 6;

    __shared__ float rA[4], rB[4];

    const int bucket = bucketc[bs];
    const int bestw = (int)(unsigned)(bestkey[bs] & 0xFFFFFFFFull);

    // haar coefficients for this (b,s): 7 scalars
    const float* hb = hcoef + b * 64;
    float hk[7];
    hk[0] = hb[0];
#pragma unroll
    for (int k = 1; k <= 6; ++k)
        hk[k] = hb[(1 << (k - 1)) + (s >> (8 - (k - 1)))];

    float h = 0.0f;
#pragma unroll
    for (int k = 0; k < 7; ++k) h += hk[k] * hemb[k * DM + t];

    // LayerNorm(haar_embed)
    float sm = h, sq = h * h;
#pragma unroll
    for (int m = 1; m < 64; m <<= 1) {
        sm += __shfl_xor(sm, m);
        sq += __shfl_xor(sq, m);
    }
    if (lane == 0) { rA[wid] = sm; rB[wid] = sq; }
    __syncthreads();
    sm = ((rA[0] + rA[1]) + rA[2]) + rA[3];
    sq = ((rB[0] + rB[1]) + rB[2]) + rB[3];
    float mh = sm * (1.0f / 256.0f);
    float vh = fmaxf(sq * (1.0f / 256.0f) - mh * mh, 0.0f);
    float hn = (h - mh) / sqrtf(vh + 1e-5f);

    // word embedding gather
    const size_t row = (size_t)bucket * W + (size_t)bestw;
    float wv = wemb[row * DM + t];

    // positional embedding on the fly
    const float cexp = -9.210340371976184f / 256.0f;  // -ln(10000)/256
    float dv = expf((float)(t & ~1) * cexp);
    float ang = (float)s * dv;
    float pe = (t & 1) ? cosf(ang) : sinf(ang);

    float o = wv + hn + pe;

    // final LayerNorm
    __syncthreads();
    float sm2 = o, sq2 = o * o;
#pragma unroll
    for (int m = 1; m < 64; m <<= 1) {
        sm2 += __shfl_xor(sm2, m);
        sq2 += __shfl_xor(sq2, m);
    }
    if (lane == 0) { rA[wid] = sm2; rB[wid] = sq2; }
    __syncthreads();
    sm2 = ((rA[0] + rA[1]) + rA[2]) + rA[3];
    sq2 = ((rB[0] + rB[1]) + rB[2]) + rB[3];
    float mo = sm2 * (1.0f / 256.0f);
    float vo = fmaxf(sq2 * (1.0f / 256.0f) - mo * mo, 0.0f);
    float on = (o - mo) / sqrtf(vo + 1e-5f);

    out[(size_t)bs * DM + t] = on;
    if (t == 0) out[(size_t)BB * SS * DM + bs] = 1.0f;  // att_mask
}

extern "C" void kernel_launch(void* const* d_in, const int* in_sizes, int n_in,
                              void* d_out, int out_size, void* d_ws, size_t ws_size,
                              hipStream_t stream) {
    const float* x     = (const float*)d_in[0];
    const float* vocab = (const float*)d_in[1];
    const float* wemb  = (const float*)d_in[2];
    const float* hemb  = (const float*)d_in[3];
    float* out = (float*)d_out;

    char* ws = (char*)d_ws;
    float* segn                  = (float*)ws;                       // 1,048,576 B
    unsigned long long* bestkey  = (unsigned long long*)(ws + 1048576); // 65,536 B
    unsigned char* bucketc       = (unsigned char*)(ws + 1048576 + 65536); // 8,192 B
    float* hco                   = (float*)(ws + 1048576 + 65536 + 8192); // 8,192 B

    prep_kernel<<<1024, 256, 0, stream>>>(x, segn, bucketc, bestkey);
    haar_kernel<<<BB, 64, 0, stream>>>(x, hco);
    search_kernel<<<512, 512, 0, stream>>>(vocab, segn, bucketc, bestkey);
    out_kernel<<<BB * SS, 256, 0, stream>>>(wemb, hemb, hco, bucketc, bestkey, out);
}

// Round 3
// 214.603 us; speedup vs baseline: 1.2401x; 1.0373x over previous
//
#include <hip/hip_runtime.h>
#include <math.h>

#define BB 32
#define TS 8192
#define DSEG 32
#define SS 256
#define DM 256
#define W 512
#define CAP 1024

// ---------------------------------------------------------------------------
// Kernel A: fused prep (blocks 0..1023) + per-batch Haar (blocks 1024..1055).
// prep arithmetic bit-identical to the passing R1 kernel.
// Haar layout per b (64 floats): [0]=a13, [1]=d13, [2..3]=d12, [4..7]=d11,
// [8..15]=d10, [16..31]=d9, [32..63]=d8
// ---------------------------------------------------------------------------
__global__ __launch_bounds__(256) void prep_haar_kernel(
    const float* __restrict__ x,
    float* __restrict__ segn_g,                 // [8192][32]
    unsigned char* __restrict__ bucketc,        // [8192]
    unsigned long long* __restrict__ bestkey,   // [8192]
    float* __restrict__ hout)                   // [32][64]
{
    const int blk = blockIdx.x;
    const int t = threadIdx.x;

    if (blk < 1024) {
        // ---------------- prep: 8 segments per block ----------------
        const int segBase = blk * 8;
        __shared__ float sseg[8][32];
        sseg[t >> 5][t & 31] = x[(size_t)segBase * 32 + t];
        __syncthreads();

        const int hw = t >> 5;        // segment slot 0..7
        const int h = hw & 1;         // half within this wave
        const int l = t & 31;
        const int seg = segBase + hw;

        float v = sseg[hw][l];
        float mn = v, mx = v, sm = v;
#pragma unroll
        for (int m = 1; m <= 16; m <<= 1) {
            mn = fminf(mn, __shfl_xor(mn, m));
            mx = fmaxf(mx, __shfl_xor(mx, m));
            sm += __shfl_xor(sm, m);
        }
        float mean = sm * (1.0f / 32.0f);
        float cm = 0.0f;
        if (l < 8) {
            cm = ((sseg[hw][4 * l] + sseg[hw][4 * l + 1]) + sseg[hw][4 * l + 2]) +
                 sseg[hw][4 * l + 3];
            cm *= 0.25f;
        }
        unsigned long long bal = __ballot(l < 8 && cm > mean);
        segn_g[(size_t)seg * 32 + l] = (v - mn) / (mx - mn + 1e-8f);
        if (l == 0) bucketc[seg] = (unsigned char)((bal >> (h * 32)) & 0xFF);
        if (l == 1) bestkey[seg] = ~0ULL;
    } else {
        // ---------------- haar: one wave per batch ----------------
        const int b = blk - 1024;
        const int lane = t;
        if (lane >= 64) return;
        const float* xb = x + (size_t)b * TS + (size_t)lane * 128;
        const float is2 = 0.70710678118654752440f;

        float a[64];  // first reduction level folded into the load
#pragma unroll
        for (int i = 0; i < 32; ++i) {
            float4 u = *(const float4*)(xb + 4 * i);
            a[2 * i + 0] = (u.x + u.y) * is2;
            a[2 * i + 1] = (u.z + u.w) * is2;
        }
#pragma unroll
        for (int len = 64; len > 1; len >>= 1) {
#pragma unroll
            for (int j = 0; j < (len >> 1); ++j)
                a[j] = (a[2 * j] + a[2 * j + 1]) * is2;
        }
        float val = a[0];  // a7[lane]
        float* ob = hout + b * 64;
#pragma unroll
        for (int len = 64; len > 1; len >>= 1) {
            float e = __shfl(val, 2 * lane);
            float o = __shfl(val, 2 * lane + 1);
            int half = len >> 1;
            if (lane < half) {
                ob[half + lane] = (e - o) * is2;
                val = (e + o) * is2;
            }
        }
        if (lane == 0) ob[0] = val;
    }
}

// ---------------------------------------------------------------------------
// Kernel B: VQ search, bucket-grouped. Block = (bucket, half). 512 threads.
// Candidate slice staged once in LDS (XOR-swizzled vs 128B-stride conflicts).
// Distance accumulation order d=0..31 — bit-identical to R0/R1 argmin.
// ---------------------------------------------------------------------------
__global__ __launch_bounds__(512) void search_kernel(
    const float* __restrict__ vocab,            // [256][512][32]
    const float* __restrict__ segn_g,
    const unsigned char* __restrict__ bucketc,
    unsigned long long* __restrict__ bestkey)
{
    const int bucket = blockIdx.x >> 1;
    const int half = blockIdx.x & 1;
    const int t = threadIdx.x;
    const int lane = t & 63;
    const int wid = t >> 6;

    __shared__ float vsh[256 * 32];   // 32 KB, swizzled
    __shared__ int list[CAP];
    __shared__ int cnt;
    if (t == 0) cnt = 0;
    __syncthreads();

    for (int i = t; i < BB * SS; i += 512) {
        if (bucketc[i] == (unsigned char)bucket) {
            int p = atomicAdd(&cnt, 1);
            if (p < CAP) list[p] = i;
        }
    }

    const float* vb = vocab + ((size_t)bucket * W + (size_t)half * 256) * DSEG;
#pragma unroll 2
    for (int f = t; f < 2048; f += 512) {     // float4 index
        int r = f >> 3, q = f & 7;
        float4 u = ((const float4*)vb)[f];
        int sq = q ^ (r & 7);
        *(float4*)&vsh[r * 32 + sq * 4] = u;
    }
    __syncthreads();

    int n = cnt; if (n > CAP) n = CAP;
    for (int i = wid; i < n; i += 8) {
        const int seg = list[i];
        const float* sp = segn_g + (size_t)seg * 32;
        float sv[32];
#pragma unroll
        for (int d = 0; d < 32; ++d) sv[d] = sp[d];

        unsigned long long best = ~0ULL;
#pragma unroll
        for (int c = 0; c < 4; ++c) {
            const int r = c * 64 + lane;
            float dist = 0.0f;
#pragma unroll
            for (int q = 0; q < 8; ++q) {
                float4 u = *(const float4*)&vsh[r * 32 + ((q ^ (r & 7)) * 4)];
                dist += fabsf(u.x - sv[4 * q + 0]);
                dist += fabsf(u.y - sv[4 * q + 1]);
                dist += fabsf(u.z - sv[4 * q + 2]);
                dist += fabsf(u.w - sv[4 * q + 3]);
            }
            unsigned w = (unsigned)(half * 256 + r);
            unsigned long long key =
                ((unsigned long long)__float_as_uint(dist) << 32) | w;
            if (key < best) best = key;
        }
#pragma unroll
        for (int m = 1; m < 64; m <<= 1) {
            unsigned long long o = __shfl_xor(best, m);
            if (o < best) best = o;
        }
        if (lane == 0) atomicMin(bestkey + seg, best);
    }
}

// ---------------------------------------------------------------------------
// Kernel C: gather + haar matvec + pos emb + 2x LayerNorm.
// One WAVE per (b,s); lane l owns dims 4l..4l+3. No LDS, no syncthreads.
// ---------------------------------------------------------------------------
__global__ __launch_bounds__(256) void out_kernel(
    const float* __restrict__ wemb,     // [131072][256]
    const float* __restrict__ hemb,     // [7][256]
    const float* __restrict__ hcoef,    // [32][64]
    const unsigned char* __restrict__ bucketc,
    const unsigned long long* __restrict__ bestkey,
    float* __restrict__ out)
{
    const int bs = (blockIdx.x << 2) + (threadIdx.x >> 6);  // segment id
    const int lane = threadIdx.x & 63;
    const int b = bs >> 8;
    const int s = bs & 255;

    const int bucket = bucketc[bs];
    const int bestw = (int)(unsigned)(bestkey[bs] & 0xFFFFFFFFull);

    // haar coefficients for this (b,s): 7 scalars (broadcast across wave)
    const float* hb = hcoef + b * 64;
    float hk[7];
    hk[0] = hb[0];
#pragma unroll
    for (int k = 1; k <= 6; ++k)
        hk[k] = hb[(1 << (k - 1)) + (s >> (8 - (k - 1)))];

    // haar matvec for 4 dims
    float h0 = 0.f, h1 = 0.f, h2 = 0.f, h3 = 0.f;
#pragma unroll
    for (int k = 0; k < 7; ++k) {
        float4 he = ((const float4*)(hemb + k * DM))[lane];
        h0 += hk[k] * he.x; h1 += hk[k] * he.y;
        h2 += hk[k] * he.z; h3 += hk[k] * he.w;
    }

    // LayerNorm(haar_embed) — wave tree reduction
    float sm = ((h0 + h1) + h2) + h3;
    float sq = ((h0 * h0 + h1 * h1) + h2 * h2) + h3 * h3;
#pragma unroll
    for (int m = 1; m < 64; m <<= 1) {
        sm += __shfl_xor(sm, m);
        sq += __shfl_xor(sq, m);
    }
    float mh = sm * (1.0f / 256.0f);
    float vh = fmaxf(sq * (1.0f / 256.0f) - mh * mh, 0.0f);
    float rs = 1.0f / sqrtf(vh + 1e-5f);
    float n0 = (h0 - mh) * rs, n1 = (h1 - mh) * rs;
    float n2 = (h2 - mh) * rs, n3 = (h3 - mh) * rs;

    // word embedding gather (coalesced float4 row read)
    const size_t row = (size_t)bucket * W + (size_t)bestw;
    float4 wv = ((const float4*)(wemb + row * DM))[lane];

    // positional embedding: dims d0=4*lane (even), d0+1, d0+2 (even), d0+3
    const float cexp = -9.210340371976184f / 256.0f;  // -ln(10000)/256
    float dva = expf((float)(4 * lane) * cexp);
    float dvb = expf((float)(4 * lane + 2) * cexp);
    float anga = (float)s * dva, angb = (float)s * dvb;
    float o0 = wv.x + n0 + sinf(anga);
    float o1 = wv.y + n1 + cosf(anga);
    float o2 = wv.z + n2 + sinf(angb);
    float o3 = wv.w + n3 + cosf(angb);

    // final LayerNorm
    float sm2 = ((o0 + o1) + o2) + o3;
    float sq2 = ((o0 * o0 + o1 * o1) + o2 * o2) + o3 * o3;
#pragma unroll
    for (int m = 1; m < 64; m <<= 1) {
        sm2 += __shfl_xor(sm2, m);
        sq2 += __shfl_xor(sq2, m);
    }
    float mo = sm2 * (1.0f / 256.0f);
    float vo = fmaxf(sq2 * (1.0f / 256.0f) - mo * mo, 0.0f);
    float rs2 = 1.0f / sqrtf(vo + 1e-5f);

    float4 res;
    res.x = (o0 - mo) * rs2; res.y = (o1 - mo) * rs2;
    res.z = (o2 - mo) * rs2; res.w = (o3 - mo) * rs2;
    ((float4*)(out + (size_t)bs * DM))[lane] = res;
    if (lane == 0) out[(size_t)BB * SS * DM + bs] = 1.0f;  // att_mask
}

extern "C" void kernel_launch(void* const* d_in, const int* in_sizes, int n_in,
                              void* d_out, int out_size, void* d_ws, size_t ws_size,
                              hipStream_t stream) {
    const float* x     = (const float*)d_in[0];
    const float* vocab = (const float*)d_in[1];
    const float* wemb  = (const float*)d_in[2];
    const float* hemb  = (const float*)d_in[3];
    float* out = (float*)d_out;

    char* ws = (char*)d_ws;
    float* segn                  = (float*)ws;                            // 1 MB
    unsigned long long* bestkey  = (unsigned long long*)(ws + 1048576);   // 64 KB
    unsigned char* bucketc       = (unsigned char*)(ws + 1048576 + 65536);    // 8 KB
    float* hco                   = (float*)(ws + 1048576 + 65536 + 8192);     // 8 KB

    prep_haar_kernel<<<1056, 256, 0, stream>>>(x, segn, bucketc, bestkey, hco);
    search_kernel<<<512, 512, 0, stream>>>(vocab, segn, bucketc, bestkey);
    out_kernel<<<2048, 256, 0, stream>>>(wemb, hemb, hco, bucketc, bestkey, out);
}

// Round 4
// 206.868 us; speedup vs baseline: 1.2865x; 1.0374x over previous
//
#include <hip/hip_runtime.h>
#include <math.h>

#define BB 32
#define TS 8192
#define DSEG 32
#define SS 256
#define DM 256
#define W 512
#define CAP 1024

// ---------------------------------------------------------------------------
// Kernel A: fused prep (blocks 0..1023) + per-batch Haar (1024..1055)
//           + pos-emb table (1056..1311).
// prep arithmetic bit-identical to the passing R2 kernel.
// ---------------------------------------------------------------------------
__global__ __launch_bounds__(256) void prep_haar_pe_kernel(
    const float* __restrict__ x,
    float* __restrict__ segn_g,                 // [8192][32]
    unsigned char* __restrict__ bucketc,        // [8192]
    unsigned long long* __restrict__ bestkey,   // [8192]
    float* __restrict__ hout,                   // [32][64]
    float* __restrict__ pe_g)                   // [256][256]
{
    const int blk = blockIdx.x;
    const int t = threadIdx.x;

    if (blk < 1024) {
        // ---------------- prep: 8 segments per block ----------------
        const int segBase = blk * 8;
        __shared__ float sseg[8][32];
        sseg[t >> 5][t & 31] = x[(size_t)segBase * 32 + t];
        __syncthreads();

        const int hw = t >> 5;        // segment slot 0..7
        const int h = hw & 1;         // half within this wave
        const int l = t & 31;
        const int seg = segBase + hw;

        float v = sseg[hw][l];
        float mn = v, mx = v, sm = v;
#pragma unroll
        for (int m = 1; m <= 16; m <<= 1) {
            mn = fminf(mn, __shfl_xor(mn, m));
            mx = fmaxf(mx, __shfl_xor(mx, m));
            sm += __shfl_xor(sm, m);
        }
        float mean = sm * (1.0f / 32.0f);
        float cm = 0.0f;
        if (l < 8) {
            cm = ((sseg[hw][4 * l] + sseg[hw][4 * l + 1]) + sseg[hw][4 * l + 2]) +
                 sseg[hw][4 * l + 3];
            cm *= 0.25f;
        }
        unsigned long long bal = __ballot(l < 8 && cm > mean);
        segn_g[(size_t)seg * 32 + l] = (v - mn) / (mx - mn + 1e-8f);
        if (l == 0) bucketc[seg] = (unsigned char)((bal >> (h * 32)) & 0xFF);
        if (l == 1) bestkey[seg] = ~0ULL;
    } else if (blk < 1056) {
        // ---------------- haar: one wave per batch ----------------
        const int b = blk - 1024;
        const int lane = t;
        if (lane >= 64) return;
        const float* xb = x + (size_t)b * TS + (size_t)lane * 128;
        const float is2 = 0.70710678118654752440f;

        float a[64];  // first reduction level folded into the load
#pragma unroll
        for (int i = 0; i < 32; ++i) {
            float4 u = *(const float4*)(xb + 4 * i);
            a[2 * i + 0] = (u.x + u.y) * is2;
            a[2 * i + 1] = (u.z + u.w) * is2;
        }
#pragma unroll
        for (int len = 64; len > 1; len >>= 1) {
#pragma unroll
            for (int j = 0; j < (len >> 1); ++j)
                a[j] = (a[2 * j] + a[2 * j + 1]) * is2;
        }
        float val = a[0];  // a7[lane]
        float* ob = hout + b * 64;
#pragma unroll
        for (int len = 64; len > 1; len >>= 1) {
            float e = __shfl(val, 2 * lane);
            float o = __shfl(val, 2 * lane + 1);
            int half = len >> 1;
            if (lane < half) {
                ob[half + lane] = (e - o) * is2;
                val = (e + o) * is2;
            }
        }
        if (lane == 0) ob[0] = val;
    } else {
        // ---------------- pos-emb table: one block per s ----------------
        const int s = blk - 1056;
        const float cexp = -9.210340371976184f / 256.0f;  // -ln(10000)/256
        float dv = expf((float)(t & ~1) * cexp);
        float ang = (float)s * dv;
        pe_g[s * DM + t] = (t & 1) ? cosf(ang) : sinf(ang);
    }
}

// ---------------------------------------------------------------------------
// Kernel B: VQ search, bucket-grouped, 2-segment batching per wave.
// Block = (bucket, half). 512 threads. Candidate slice staged once in LDS
// (XOR-swizzled). Distance order d=0..31 — bit-identical argmin vs R2.
// ---------------------------------------------------------------------------
__global__ __launch_bounds__(512) void search_kernel(
    const float* __restrict__ vocab,            // [256][512][32]
    const float* __restrict__ segn_g,
    const unsigned char* __restrict__ bucketc,
    unsigned long long* __restrict__ bestkey)
{
    const int bucket = blockIdx.x >> 1;
    const int half = blockIdx.x & 1;
    const int t = threadIdx.x;
    const int lane = t & 63;
    const int wid = t >> 6;

    __shared__ float vsh[256 * 32];   // 32 KB, swizzled
    __shared__ int list[CAP];
    __shared__ int cnt;
    if (t == 0) cnt = 0;
    __syncthreads();

    // scan for members of this bucket: 16 bytes per thread, one uint4 load
    {
        uint4 v16 = ((const uint4*)bucketc)[t];
        const unsigned char* pb = (const unsigned char*)&v16;
        int base = t * 16;
#pragma unroll
        for (int j = 0; j < 16; ++j) {
            if (pb[j] == (unsigned char)bucket) {
                int p = atomicAdd(&cnt, 1);
                if (p < CAP) list[p] = base + j;
            }
        }
    }

    // stage candidate half-slice: 256 rows x 32 floats
    const float* vb = vocab + ((size_t)bucket * W + (size_t)half * 256) * DSEG;
#pragma unroll 2
    for (int f = t; f < 2048; f += 512) {     // float4 index
        int r = f >> 3, q = f & 7;
        float4 u = ((const float4*)vb)[f];
        int sq = q ^ (r & 7);
        *(float4*)&vsh[r * 32 + sq * 4] = u;
    }
    __syncthreads();

    int n = cnt; if (n > CAP) n = CAP;
    for (int i = 2 * wid; i < n; i += 16) {
        const int segA = list[i];
        const bool hasB = (i + 1 < n);
        const int segB = hasB ? list[i + 1] : segA;
        const float* spA = segn_g + (size_t)segA * 32;
        const float* spB = segn_g + (size_t)segB * 32;
        float svA[32], svB[32];
#pragma unroll
        for (int d = 0; d < 32; ++d) { svA[d] = spA[d]; svB[d] = spB[d]; }

        unsigned long long bestA = ~0ULL, bestB = ~0ULL;
#pragma unroll
        for (int c = 0; c < 4; ++c) {
            const int r = c * 64 + lane;
            float dA = 0.0f, dB = 0.0f;
#pragma unroll
            for (int q = 0; q < 8; ++q) {
                float4 u = *(const float4*)&vsh[r * 32 + ((q ^ (r & 7)) * 4)];
                dA += fabsf(u.x - svA[4 * q + 0]);
                dA += fabsf(u.y - svA[4 * q + 1]);
                dA += fabsf(u.z - svA[4 * q + 2]);
                dA += fabsf(u.w - svA[4 * q + 3]);
                dB += fabsf(u.x - svB[4 * q + 0]);
                dB += fabsf(u.y - svB[4 * q + 1]);
                dB += fabsf(u.z - svB[4 * q + 2]);
                dB += fabsf(u.w - svB[4 * q + 3]);
            }
            unsigned w = (unsigned)(half * 256 + r);
            unsigned long long kA =
                ((unsigned long long)__float_as_uint(dA) << 32) | w;
            unsigned long long kB =
                ((unsigned long long)__float_as_uint(dB) << 32) | w;
            if (kA < bestA) bestA = kA;
            if (kB < bestB) bestB = kB;
        }
#pragma unroll
        for (int m = 1; m < 64; m <<= 1) {
            unsigned long long oA = __shfl_xor(bestA, m);
            unsigned long long oB = __shfl_xor(bestB, m);
            if (oA < bestA) bestA = oA;
            if (oB < bestB) bestB = oB;
        }
        if (lane == 0) {
            atomicMin(bestkey + segA, bestA);
            if (hasB) atomicMin(bestkey + segB, bestB);
        }
    }
}

// ---------------------------------------------------------------------------
// Kernel C: gather + haar matvec + pe-table add + 2x LayerNorm.
// One WAVE per (b,s); lane l owns dims 4l..4l+3. No LDS, no syncthreads.
// ---------------------------------------------------------------------------
__global__ __launch_bounds__(256) void out_kernel(
    const float* __restrict__ wemb,     // [131072][256]
    const float* __restrict__ hemb,     // [7][256]
    const float* __restrict__ hcoef,    // [32][64]
    const float* __restrict__ pe_g,     // [256][256]
    const unsigned char* __restrict__ bucketc,
    const unsigned long long* __restrict__ bestkey,
    float* __restrict__ out)
{
    const int bs = (blockIdx.x << 2) + (threadIdx.x >> 6);  // segment id
    const int lane = threadIdx.x & 63;
    const int b = bs >> 8;
    const int s = bs & 255;

    const int bucket = bucketc[bs];
    const int bestw = (int)(unsigned)(bestkey[bs] & 0xFFFFFFFFull);

    // haar coefficients for this (b,s): 7 scalars (broadcast across wave)
    const float* hb = hcoef + b * 64;
    float hk[7];
    hk[0] = hb[0];
#pragma unroll
    for (int k = 1; k <= 6; ++k)
        hk[k] = hb[(1 << (k - 1)) + (s >> (8 - (k - 1)))];

    // haar matvec for 4 dims
    float h0 = 0.f, h1 = 0.f, h2 = 0.f, h3 = 0.f;
#pragma unroll
    for (int k = 0; k < 7; ++k) {
        float4 he = ((const float4*)(hemb + k * DM))[lane];
        h0 += hk[k] * he.x; h1 += hk[k] * he.y;
        h2 += hk[k] * he.z; h3 += hk[k] * he.w;
    }

    // LayerNorm(haar_embed) — wave tree reduction
    float sm = ((h0 + h1) + h2) + h3;
    float sq = ((h0 * h0 + h1 * h1) + h2 * h2) + h3 * h3;
#pragma unroll
    for (int m = 1; m < 64; m <<= 1) {
        sm += __shfl_xor(sm, m);
        sq += __shfl_xor(sq, m);
    }
    float mh = sm * (1.0f / 256.0f);
    float vh = fmaxf(sq * (1.0f / 256.0f) - mh * mh, 0.0f);
    float rs = 1.0f / sqrtf(vh + 1e-5f);
    float n0 = (h0 - mh) * rs, n1 = (h1 - mh) * rs;
    float n2 = (h2 - mh) * rs, n3 = (h3 - mh) * rs;

    // word embedding gather (coalesced float4 row read)
    const size_t row = (size_t)bucket * W + (size_t)bestw;
    float4 wv = ((const float4*)(wemb + row * DM))[lane];

    // positional embedding from table
    float4 pv = ((const float4*)(pe_g + s * DM))[lane];

    float o0 = wv.x + n0 + pv.x;
    float o1 = wv.y + n1 + pv.y;
    float o2 = wv.z + n2 + pv.z;
    float o3 = wv.w + n3 + pv.w;

    // final LayerNorm
    float sm2 = ((o0 + o1) + o2) + o3;
    float sq2 = ((o0 * o0 + o1 * o1) + o2 * o2) + o3 * o3;
#pragma unroll
    for (int m = 1; m < 64; m <<= 1) {
        sm2 += __shfl_xor(sm2, m);
        sq2 += __shfl_xor(sq2, m);
    }
    float mo = sm2 * (1.0f / 256.0f);
    float vo = fmaxf(sq2 * (1.0f / 256.0f) - mo * mo, 0.0f);
    float rs2 = 1.0f / sqrtf(vo + 1e-5f);

    float4 res;
    res.x = (o0 - mo) * rs2; res.y = (o1 - mo) * rs2;
    res.z = (o2 - mo) * rs2; res.w = (o3 - mo) * rs2;
    ((float4*)(out + (size_t)bs * DM))[lane] = res;
    if (lane == 0) out[(size_t)BB * SS * DM + bs] = 1.0f;  // att_mask
}

extern "C" void kernel_launch(void* const* d_in, const int* in_sizes, int n_in,
                              void* d_out, int out_size, void* d_ws, size_t ws_size,
                              hipStream_t stream) {
    const float* x     = (const float*)d_in[0];
    const float* vocab = (const float*)d_in[1];
    const float* wemb  = (const float*)d_in[2];
    const float* hemb  = (const float*)d_in[3];
    float* out = (float*)d_out;

    char* ws = (char*)d_ws;
    float* segn                  = (float*)ws;                              // 1 MB
    unsigned long long* bestkey  = (unsigned long long*)(ws + 1048576);     // 64 KB
    unsigned char* bucketc       = (unsigned char*)(ws + 1048576 + 65536);  // 8 KB
    float* hco                   = (float*)(ws + 1048576 + 65536 + 8192);   // 8 KB
    float* pe_g                  = (float*)(ws + 1048576 + 65536 + 16384);  // 256 KB

    prep_haar_pe_kernel<<<1312, 256, 0, stream>>>(x, segn, bucketc, bestkey,
                                                  hco, pe_g);
    search_kernel<<<512, 512, 0, stream>>>(vocab, segn, bucketc, bestkey);
    out_kernel<<<2048, 256, 0, stream>>>(wemb, hemb, hco, pe_g, bucketc,
                                         bestkey, out);
}